// Round 1
// baseline (661.099 us; speedup 1.0000x reference)
//
#include <hip/hip_runtime.h>
#include <hip/hip_bf16.h>
#include <math.h>

#define B_ 8
#define M_ 4096
#define D_ 1024
#define NP_ 128
#define TEMP_ 0.1f
#define EPS_ 1e-12f

typedef __attribute__((ext_vector_type(8))) short bf16x8;
typedef __attribute__((ext_vector_type(4))) float f32x4;

__device__ __forceinline__ unsigned short f2bf(float f) {
    union { float f; unsigned int u; } v; v.f = f;
    unsigned int u = v.u;
    u += 0x7fff + ((u >> 16) & 1);  // RNE
    return (unsigned short)(u >> 16);
}

// stage 128 rows x 64 bytes into LDS (8 KB), via global_load_lds width 16.
__device__ __forceinline__ void stage_tile(const char* gbase, size_t row_stride,
                                           char* lds, int tid) {
    const int lane = tid & 63, w = tid >> 6;
#pragma unroll
    for (int t = 0; t < 2; ++t) {
        const int row = w * 32 + t * 16 + (lane >> 2);
        const char* g = gbase + (size_t)row * row_stride + (lane & 3) * 16;
        char* l = lds + (w * 32 + t * 16) * 64 + lane * 16;
        __builtin_amdgcn_global_load_lds((const __attribute__((address_space(1))) unsigned int*)g,
                                         (__attribute__((address_space(3))) unsigned int*)l,
                                         16, 0, 0);
    }
}

// stage 64 rows x 64 bytes into LDS (4 KB)
__device__ __forceinline__ void stage_rows64(const char* gbase, size_t row_stride,
                                             char* lds, int tid) {
    const int lane = tid & 63, w = tid >> 6;
    const int row = w * 16 + (lane >> 2);
    const char* g = gbase + (size_t)row * row_stride + (lane & 3) * 16;
    char* l = lds + (w * 16) * 64 + lane * 16;
    __builtin_amdgcn_global_load_lds((const __attribute__((address_space(1))) unsigned int*)g,
                                     (__attribute__((address_space(3))) unsigned int*)l,
                                     16, 0, 0);
}

template <int NI, int NJ>
__device__ __forceinline__ void mfma_tile(const char* At, const char* Bt,
                                          f32x4 (&acc)[NI][NJ], int wm, int wn,
                                          int fr, int q) {
    bf16x8 a[NI], bb[NJ];
#pragma unroll
    for (int i = 0; i < NI; ++i)
        a[i] = *(const bf16x8*)(At + (wm + i * 16 + fr) * 64 + q * 16);
#pragma unroll
    for (int j = 0; j < NJ; ++j)
        bb[j] = *(const bf16x8*)(Bt + (wn + j * 16 + fr) * 64 + q * 16);
#pragma unroll
    for (int i = 0; i < NI; ++i)
#pragma unroll
        for (int j = 0; j < NJ; ++j)
            acc[i][j] = __builtin_amdgcn_mfma_f32_16x16x32_bf16(a[i], bb[j], acc[i][j], 0, 0, 0);
}

// ---------------- prep: rinv + bf16 cast (xbf[m][d]) + bf16 transpose (xbfT[d][m]) ----------------
__global__ __launch_bounds__(256) void k_prepT(const float* __restrict__ x,
                                               unsigned short* __restrict__ xbf,
                                               unsigned short* __restrict__ xbfT,
                                               float* __restrict__ rinv) {
    const int p = blockIdx.x;
    const int b = p >> 6, m0 = (p & 63) * 64;
    const int tid = threadIdx.x;
    const int mg = tid >> 4;   // 0..15
    const int d4 = tid & 15;   // 0..15
    __shared__ unsigned short lt[2][64][72];  // double-buffered: one barrier per chunk
    float ss[4] = {0.f, 0.f, 0.f, 0.f};
    for (int ch = 0; ch < 16; ++ch) {
        const int d0 = ch * 64;
        const int buf = ch & 1;
#pragma unroll
        for (int ii = 0; ii < 4; ++ii) {
            const int m = mg + ii * 16;
            float4 v = *(const float4*)(x + ((size_t)(b * M_ + m0 + m)) * D_ + d0 + d4 * 4);
            ss[ii] += v.x * v.x + v.y * v.y + v.z * v.z + v.w * v.w;
            ushort4 bv;
            bv.x = f2bf(v.x); bv.y = f2bf(v.y); bv.z = f2bf(v.z); bv.w = f2bf(v.w);
            *(ushort4*)(xbf + ((size_t)(b * M_ + m0 + m)) * D_ + d0 + d4 * 4) = bv;
            lt[buf][d4 * 4 + 0][m] = bv.x;
            lt[buf][d4 * 4 + 1][m] = bv.y;
            lt[buf][d4 * 4 + 2][m] = bv.z;
            lt[buf][d4 * 4 + 3][m] = bv.w;
        }
        __syncthreads();
        const int dl = tid >> 2, mq = (tid & 3) * 16;
        bf16x8 v0 = *(const bf16x8*)&lt[buf][dl][mq];
        bf16x8 v1 = *(const bf16x8*)&lt[buf][dl][mq + 8];
        unsigned short* to = xbfT + ((size_t)(b * D_ + d0 + dl)) * M_ + m0 + mq;
        *(bf16x8*)(to) = v0;
        *(bf16x8*)(to + 8) = v1;
        // no second barrier: next chunk writes the other buffer
    }
#pragma unroll
    for (int ii = 0; ii < 4; ++ii) {
        float s = ss[ii];
        s += __shfl_down(s, 8, 16);
        s += __shfl_down(s, 4, 16);
        s += __shfl_down(s, 2, 16);
        s += __shfl_down(s, 1, 16);
        if (d4 == 0)
            rinv[b * M_ + m0 + mg + ii * 16] = 1.0f / (fmaxf(sqrtf(s), EPS_) * TEMP_);
    }
}

// ---------------- phi normalize -> phinT[np][d] bf16 ----------------
__global__ void k_phin(const float* __restrict__ phi, const float* __restrict__ scale,
                       unsigned short* __restrict__ phinT) {
    const int np = blockIdx.x, tid = threadIdx.x;
    float ss = 0.f;
    for (int d = tid; d < D_; d += 256) {
        float v = phi[d * NP_ + np];
        ss += v * v;
    }
    __shared__ float red[256];
    red[tid] = ss;
    __syncthreads();
    for (int s = 128; s > 0; s >>= 1) {
        if (tid < s) red[tid] += red[tid + s];
        __syncthreads();
    }
    float inv = scale[0] / fmaxf(sqrtf(red[0]), EPS_);
    for (int d = tid; d < D_; d += 256) phinT[np * D_ + d] = f2bf(phi[d * NP_ + np] * inv);
}

// ---------------- GEMM1: logitsT[b][np][m] = (phinT . xbf) * rinv[m] ----------------
// tile 128np x 64m, grid (64, 8) = 512 blocks (2 blocks/CU), 2-phase double-buffered
__global__ __launch_bounds__(256) void k_logits(const unsigned short* __restrict__ phinT,
                                                const unsigned short* __restrict__ xbf,
                                                const float* __restrict__ rinv,
                                                float* __restrict__ logitsT) {
    const int b = blockIdx.y, m0 = blockIdx.x * 64;
    const int tid = threadIdx.x, lane = tid & 63, w = tid >> 6;
    __shared__ char At[2][8192], Bt[2][4096];
    f32x4 acc[4][2] = {};
    const char* abase = (const char*)phinT;  // 128 np rows, stride 2048 B
    const char* bbase = (const char*)(xbf + ((size_t)b * M_ + m0) * D_);  // 64 m rows
    const int wm = (w & 1) * 64, wn = (w >> 1) * 32;
    const int fr = lane & 15, q = lane >> 4;
    stage_tile(abase, 2048, At[0], tid);
    stage_rows64(bbase, 2048, Bt[0], tid);
    __syncthreads();
    int cur = 0;
    for (int k0 = 64; k0 < 2048; k0 += 64) {
        stage_tile(abase + k0, 2048, At[cur ^ 1], tid);
        stage_rows64(bbase + k0, 2048, Bt[cur ^ 1], tid);
        mfma_tile<4, 2>(At[cur], Bt[cur], acc, wm, wn, fr, q);
        __syncthreads();
        cur ^= 1;
    }
    mfma_tile<4, 2>(At[cur], Bt[cur], acc, wm, wn, fr, q);
#pragma unroll
    for (int j = 0; j < 2; ++j) {
        const int m = m0 + wn + j * 16 + fr;
        const float r = rinv[b * M_ + m];
#pragma unroll
        for (int i = 0; i < 4; ++i) {
            const int nprow = wm + i * 16 + q * 4;
#pragma unroll
            for (int reg = 0; reg < 4; ++reg)
                logitsT[((size_t)b * NP_ + nprow + reg) * M_ + m] = acc[i][j][reg] * r;
        }
    }
}

// ---------------- dispatch softmax stats over m (rows of logitsT) ----------------
__global__ void k_colstats(const float* __restrict__ logitsT, float* __restrict__ cmax,
                           float* __restrict__ cinv) {
    const int row = blockIdx.x * 4 + (threadIdx.x >> 6);  // b*128+np
    const int lane = threadIdx.x & 63;
    const float4* base = (const float4*)(logitsT + (size_t)row * M_);
    float mx = -1e30f, sm = 0.f;
#pragma unroll 4
    for (int it = 0; it < 16; ++it) {
        float4 v = base[lane + 64 * it];
        float lm = fmaxf(fmaxf(v.x, v.y), fmaxf(v.z, v.w));
        float nm = fmaxf(mx, lm);
        sm = sm * __expf(mx - nm) + __expf(v.x - nm) + __expf(v.y - nm) + __expf(v.z - nm) +
             __expf(v.w - nm);
        mx = nm;
    }
    for (int off = 32; off > 0; off >>= 1) {
        float om = __shfl_down(mx, off), os = __shfl_down(sm, off);
        float nm = fmaxf(mx, om);
        sm = sm * __expf(mx - nm) + os * __expf(om - nm);
        mx = nm;
    }
    if (lane == 0) {
        cmax[row] = mx;
        cinv[row] = 1.0f / sm;
    }
}

// ---------------- weights: dvalT[np][m] bf16 (dispatch), cbf[m][np] bf16 (combine) ----------------
__global__ __launch_bounds__(256) void k_weights(const float* __restrict__ logitsT,
                                                 const float* __restrict__ cmax,
                                                 const float* __restrict__ cinv,
                                                 unsigned short* __restrict__ dvalT,
                                                 unsigned short* __restrict__ cbf) {
    const int b = blockIdx.y, m0 = blockIdx.x * 32;
    const int tid = threadIdx.x;
    __shared__ float lt[128][36];
    __shared__ float red[32][8];
    __shared__ float rstat[32][2];
    const int np = tid >> 1;
    const int mh = (tid & 1) * 16;
    const float cm = cmax[b * NP_ + np], ci = cinv[b * NP_ + np];
#pragma unroll
    for (int ii = 0; ii < 4; ++ii) {
        const int mq = mh + ii * 4;
        float4 v = *(const float4*)(logitsT + ((size_t)b * NP_ + np) * M_ + m0 + mq);
        *(float4*)&lt[np][mq] = v;
        ushort4 e;
        e.x = f2bf(__expf(v.x - cm) * ci);
        e.y = f2bf(__expf(v.y - cm) * ci);
        e.z = f2bf(__expf(v.z - cm) * ci);
        e.w = f2bf(__expf(v.w - cm) * ci);
        *(ushort4*)(dvalT + ((size_t)b * NP_ + np) * M_ + m0 + mq) = e;
    }
    __syncthreads();
    const int mm = tid >> 3, g = tid & 7;
    float mx = -1e30f;
#pragma unroll
    for (int i = 0; i < 16; ++i) mx = fmaxf(mx, lt[g * 16 + i][mm]);
    red[mm][g] = mx;
    __syncthreads();
    if (g == 0) {
        float M2 = red[mm][0];
#pragma unroll
        for (int k = 1; k < 8; ++k) M2 = fmaxf(M2, red[mm][k]);
        rstat[mm][0] = M2;
    }
    __syncthreads();
    const float rm = rstat[mm][0];
    float s = 0.f;
#pragma unroll
    for (int i = 0; i < 16; ++i) s += __expf(lt[g * 16 + i][mm] - rm);
    red[mm][g] = s;
    __syncthreads();
    if (g == 0) {
        float S = 0.f;
#pragma unroll
        for (int k = 0; k < 8; ++k) S += red[mm][k];
        rstat[mm][1] = 1.0f / S;
    }
    __syncthreads();
    const float ri = rstat[mm][1];
    bf16x8 o0, o1;
#pragma unroll
    for (int i = 0; i < 8; ++i) o0[i] = (short)f2bf(__expf(lt[g * 16 + i][mm] - rm) * ri);
#pragma unroll
    for (int i = 0; i < 8; ++i) o1[i] = (short)f2bf(__expf(lt[g * 16 + 8 + i][mm] - rm) * ri);
    unsigned short* co = cbf + ((size_t)b * M_ + m0 + mm) * NP_ + g * 16;
    *(bf16x8*)(co) = o0;
    *(bf16x8*)(co + 8) = o1;
}

// ---------------- GEMM2: partial[kc][b][np][d] = dvalT-chunk . xbfT-chunk ----------------
// split-K = 8 -> grid (8, 8, 8) = 512 blocks, 2-phase double-buffered
__global__ __launch_bounds__(256) void k_xs(const unsigned short* __restrict__ dvalT,
                                            const unsigned short* __restrict__ xbfT,
                                            float* __restrict__ partial) {
    const int dt = blockIdx.x, kc = blockIdx.y, b = blockIdx.z;
    const int d0 = dt * 128;
    const int tid = threadIdx.x, lane = tid & 63, w = tid >> 6;
    __shared__ char At[2][8192], Bt[2][8192];
    f32x4 acc[4][4] = {};
    const char* abase = (const char*)(dvalT + (size_t)b * NP_ * M_) + (size_t)kc * 1024;
    const char* bbase = (const char*)(xbfT + ((size_t)b * D_ + d0) * M_) + (size_t)kc * 1024;
    const int wm = (w & 1) * 64, wn = (w >> 1) * 64;
    const int fr = lane & 15, q = lane >> 4;
    stage_tile(abase, (size_t)M_ * 2, At[0], tid);
    stage_tile(bbase, (size_t)M_ * 2, Bt[0], tid);
    __syncthreads();
    int cur = 0;
    for (int k0 = 64; k0 < 1024; k0 += 64) {
        stage_tile(abase + k0, (size_t)M_ * 2, At[cur ^ 1], tid);
        stage_tile(bbase + k0, (size_t)M_ * 2, Bt[cur ^ 1], tid);
        mfma_tile<4, 4>(At[cur], Bt[cur], acc, wm, wn, fr, q);
        __syncthreads();
        cur ^= 1;
    }
    mfma_tile<4, 4>(At[cur], Bt[cur], acc, wm, wn, fr, q);
#pragma unroll
    for (int j = 0; j < 4; ++j) {
        const int d = d0 + wn + j * 16 + fr;
#pragma unroll
        for (int i = 0; i < 4; ++i) {
            const int nprow = wm + i * 16 + q * 4;
#pragma unroll
            for (int reg = 0; reg < 4; ++reg)
                partial[(((size_t)kc * B_ + b) * NP_ + nprow + reg) * D_ + d] = acc[i][j][reg];
        }
    }
}

// ---------------- reduce split-K partials (8) -> xs[b][np][d] fp32 ----------------
__global__ void k_xsred(const float* __restrict__ partial, float* __restrict__ xs) {
    const size_t i = ((size_t)blockIdx.x * 256 + threadIdx.x) * 4;
    const size_t CH = (size_t)B_ * NP_ * D_;
    float4 o = *(const float4*)(partial + i);
#pragma unroll
    for (int c = 1; c < 8; ++c) {
        float4 s = *(const float4*)(partial + (size_t)c * CH + i);
        o.x += s.x; o.y += s.y; o.z += s.z; o.w += s.w;
    }
    *(float4*)(xs + i) = o;
}

// ---------------- per-expert linear: ysT[b][e][np] bf16 = xs @ W[n] + bias[n] ----------------
__global__ __launch_bounds__(256) void k_ys(const float* __restrict__ xs,
                                            const float* __restrict__ W,
                                            const float* __restrict__ bias,
                                            unsigned short* __restrict__ ysT) {
    const int et = blockIdx.x;  // 8 tiles of 128 e
    const int n = blockIdx.y;   // 64
    const int e0 = et * 128;
    const int tid = threadIdx.x, tx = tid & 31, ty = tid >> 5;
    __shared__ float wt[32][128];
    __shared__ float xst[16][32];
    float acc[2][4];
#pragma unroll
    for (int j = 0; j < 2; ++j)
#pragma unroll
        for (int q = 0; q < 4; ++q) acc[j][q] = 0.f;
    const float* wbase = W + (size_t)n * D_ * D_;
    for (int k0 = 0; k0 < D_; k0 += 32) {
#pragma unroll
        for (int it = 0; it < 4; ++it) {
            int idx = tid + 256 * it;
            int row = idx >> 5, c4 = (idx & 31) * 4;
            *(float4*)(&wt[row][c4]) = *(const float4*)(wbase + (size_t)(k0 + row) * D_ + e0 + c4);
        }
        if (tid < 128) {
            int r = tid >> 3, c4 = (tid & 7) * 4;
            int bb = r >> 1, pp = r & 1;
            *(float4*)(&xst[r][c4]) =
                *(const float4*)(xs + ((size_t)bb * NP_ + n * 2 + pp) * D_ + k0 + c4);
        }
        __syncthreads();
#pragma unroll
        for (int k = 0; k < 32; ++k) {
            float4 w4 = *(const float4*)(&wt[k][tx * 4]);
            float r0 = xst[ty * 2][k], r1 = xst[ty * 2 + 1][k];
            acc[0][0] += r0 * w4.x; acc[0][1] += r0 * w4.y;
            acc[0][2] += r0 * w4.z; acc[0][3] += r0 * w4.w;
            acc[1][0] += r1 * w4.x; acc[1][1] += r1 * w4.y;
            acc[1][2] += r1 * w4.z; acc[1][3] += r1 * w4.w;
        }
        __syncthreads();
    }
    float4 bv = *(const float4*)(bias + n * D_ + e0 + tx * 4);
#pragma unroll
    for (int j = 0; j < 2; ++j) {
        const int r = ty * 2 + j;
        const int bb = r >> 1, pp = r & 1;
        float v0 = acc[j][0] + bv.x, v1 = acc[j][1] + bv.y;
        float v2 = acc[j][2] + bv.z, v3 = acc[j][3] + bv.w;
        ysT[((size_t)bb * D_ + e0 + tx * 4 + 0) * NP_ + n * 2 + pp] = f2bf(v0);
        ysT[((size_t)bb * D_ + e0 + tx * 4 + 1) * NP_ + n * 2 + pp] = f2bf(v1);
        ysT[((size_t)bb * D_ + e0 + tx * 4 + 2) * NP_ + n * 2 + pp] = f2bf(v2);
        ysT[((size_t)bb * D_ + e0 + tx * 4 + 3) * NP_ + n * 2 + pp] = f2bf(v3);
    }
}

// ---------------- GEMM3: out[b][m][e] = cbf . ysT + x  (2-phase) ----------------
__global__ __launch_bounds__(256) void k_final(const unsigned short* __restrict__ cbf,
                                               const unsigned short* __restrict__ ysT,
                                               const float* __restrict__ x,
                                               float* __restrict__ out) {
    const int et = blockIdx.x, mt = blockIdx.y, b = blockIdx.z;
    const int e0 = et * 128, m0 = mt * 128;
    const int tid = threadIdx.x, lane = tid & 63, w = tid >> 6;
    __shared__ char At[2][8192], Bt[2][8192];
    f32x4 acc[4][4] = {};
    const char* abase = (const char*)(cbf + ((size_t)b * M_ + m0) * NP_);  // stride 256 B
    const char* bbase = (const char*)(ysT + ((size_t)b * D_ + e0) * NP_);  // stride 256 B
    const int wm = (w & 1) * 64, wn = (w >> 1) * 64;
    const int fr = lane & 15, q = lane >> 4;
    stage_tile(abase, 256, At[0], tid);
    stage_tile(bbase, 256, Bt[0], tid);
    __syncthreads();
    int cur = 0;
    for (int k0 = 64; k0 < 256; k0 += 64) {
        stage_tile(abase + k0, 256, At[cur ^ 1], tid);
        stage_tile(bbase + k0, 256, Bt[cur ^ 1], tid);
        mfma_tile<4, 4>(At[cur], Bt[cur], acc, wm, wn, fr, q);
        __syncthreads();
        cur ^= 1;
    }
    mfma_tile<4, 4>(At[cur], Bt[cur], acc, wm, wn, fr, q);
#pragma unroll
    for (int i = 0; i < 4; ++i) {
#pragma unroll
        for (int reg = 0; reg < 4; ++reg) {
            const int m = m0 + wm + i * 16 + q * 4 + reg;
#pragma unroll
            for (int j = 0; j < 4; ++j) {
                const int e = e0 + wn + j * 16 + fr;
                const size_t idx = ((size_t)b * M_ + m) * D_ + e;
                out[idx] = acc[i][j][reg] + x[idx];
            }
        }
    }
}

extern "C" void kernel_launch(void* const* d_in, const int* in_sizes, int n_in,
                              void* d_out, int out_size, void* d_ws, size_t ws_size,
                              hipStream_t stream) {
    const float* x = (const float*)d_in[0];
    const float* phi = (const float*)d_in[1];
    const float* scale = (const float*)d_in[2];
    const float* W = (const float*)d_in[3];
    const float* bias = (const float*)d_in[4];
    float* out = (float*)d_out;

    char* ws = (char*)d_ws;
    float* rinv = (float*)ws;                                   // 131072 B
    float* cmax = (float*)(ws + 131072);                        // 4096 B
    float* cinv = (float*)(ws + 135168);                        // 4096 B
    unsigned short* phinT = (unsigned short*)(ws + 139264);     // 262144 B
    unsigned short* xbf = (unsigned short*)(ws + 401408);       // 64 MiB
    unsigned short* xbfT = (unsigned short*)(ws + 401408 + 67108864);   // 64 MiB
    float* logitsT = (float*)(ws + 401408 + 134217728);         // 16 MiB
    unsigned short* dvalT = (unsigned short*)(ws + 401408 + 150994944);  // 8 MiB
    unsigned short* cbf = (unsigned short*)(ws + 401408 + 159383552);    // 8 MiB
    // aliases (lifetime-disjoint) — all inside the dead xbf region (64 MiB):
    float* partial = (float*)xbf;                                   // 32 MiB (8 chunks)
    float* xs = (float*)((char*)xbf + 33554432);                    // 4 MiB
    unsigned short* ysT = (unsigned short*)((char*)xbf + 37748736); // 2 MiB

    k_prepT<<<512, 256, 0, stream>>>(x, xbf, xbfT, rinv);
    k_phin<<<128, 256, 0, stream>>>(phi, scale, phinT);
    k_logits<<<dim3(64, 8), 256, 0, stream>>>(phinT, xbf, rinv, logitsT);
    k_colstats<<<256, 256, 0, stream>>>(logitsT, cmax, cinv);
    k_weights<<<dim3(128, 8), 256, 0, stream>>>(logitsT, cmax, cinv, dvalT, cbf);
    k_xs<<<dim3(8, 8, 8), 256, 0, stream>>>(dvalT, xbfT, partial);
    k_xsred<<<1024, 256, 0, stream>>>(partial, xs);
    k_ys<<<dim3(8, 64), 256, 0, stream>>>(xs, W, bias, ysT);
    k_final<<<dim3(8, 32, 8), 256, 0, stream>>>(cbf, ysT, x, out);
}